// Round 19
// baseline (178.477 us; speedup 1.0000x reference)
//
#include <hip/hip_runtime.h>
#include <hip/hip_bf16.h>

#define N_NODES 50000
#define N_EDGES 1000000
#define DIM 64
#define N_GRAPHS 64
#define OUT_DIM 8
#define NBLK_SCAN 196         // ceil(50000/256)
#define NPART 8               // one dst-range partition per XCD
#define SUBBLK 16             // blocks per partition (count_priv / fill_det)
#define NODES_PER_PART (N_NODES / NPART)   // 6250
#define NB_RP 512             // chunked radix-partition blocks
#define CHUNK_E4 489          // ceil(250000/512)
#define B_STRIDE 8192         // bf16 elements per packed weight layer (128x64)
#define LMPAD 80              // LDS mean-row stride (shorts): 160B, 16B-aligned
#define XCVT_BLOCKS 3125      // N_NODES*DIM/4/256

typedef __attribute__((ext_vector_type(8))) short short8;   // 8 bf16 = 4 VGPR
typedef __attribute__((ext_vector_type(4))) float f32x4;    // MFMA C/D
typedef __attribute__((ext_vector_type(4))) int v4i;

__device__ __forceinline__ unsigned short f2b(float f) {
    __hip_bfloat16 h = __float2bfloat16(f);
    return *reinterpret_cast<unsigned short*>(&h);
}
__device__ __forceinline__ float b2f(unsigned short u) {
    __hip_bfloat16 h = *reinterpret_cast<__hip_bfloat16*>(&u);
    return __bfloat162float(h);
}

// ---------------------------------------------------------------------------
// histB: per-chunk 8-bucket counts (VGPR if-chain + shfl reduce).
// ---------------------------------------------------------------------------
__global__ void histB_kernel(const int* __restrict__ dst, int* __restrict__ blockcnt) {
    __shared__ int sc[NPART];
    if (threadIdx.x < NPART) sc[threadIdx.x] = 0;
    __syncthreads();

    int e4lo = blockIdx.x * CHUNK_E4;
    int e4hi = e4lo + CHUNK_E4; if (e4hi > N_EDGES / 4) e4hi = N_EDGES / 4;

    int c0 = 0, c1 = 0, c2 = 0, c3 = 0, c4 = 0, c5 = 0, c6 = 0, c7 = 0;
    for (int e4 = e4lo + threadIdx.x; e4 < e4hi; e4 += 256) {
        v4i d = ((const v4i*)dst)[e4];
#define CNT1(DD)                                                              \
        {                                                                     \
            unsigned p = (unsigned)(DD) / NODES_PER_PART;                     \
            c0 += (p == 0); c1 += (p == 1); c2 += (p == 2); c3 += (p == 3);   \
            c4 += (p == 4); c5 += (p == 5); c6 += (p == 6); c7 += (p == 7);   \
        }
        CNT1(d.x) CNT1(d.y) CNT1(d.z) CNT1(d.w)
#undef CNT1
    }
    #pragma unroll
    for (int off = 32; off > 0; off >>= 1) {
        c0 += __shfl_xor(c0, off); c1 += __shfl_xor(c1, off);
        c2 += __shfl_xor(c2, off); c3 += __shfl_xor(c3, off);
        c4 += __shfl_xor(c4, off); c5 += __shfl_xor(c5, off);
        c6 += __shfl_xor(c6, off); c7 += __shfl_xor(c7, off);
    }
    if ((threadIdx.x & 63) == 0) {
        atomicAdd(&sc[0], c0); atomicAdd(&sc[1], c1);
        atomicAdd(&sc[2], c2); atomicAdd(&sc[3], c3);
        atomicAdd(&sc[4], c4); atomicAdd(&sc[5], c5);
        atomicAdd(&sc[6], c6); atomicAdd(&sc[7], c7);
    }
    __syncthreads();
    if (threadIdx.x < NPART) blockcnt[blockIdx.x * NPART + threadIdx.x] = sc[threadIdx.x];
}

// ---------------------------------------------------------------------------
// scatterP (R19: scan8 inlined): each block redundantly scans the 4096
// bucket-major blockcnt entries in LDS (R17-phase1-proven code), extracts
// its own 8 cursors, block 0 writes bucket_base. Then the bucketed scatter.
// ---------------------------------------------------------------------------
__global__ void scatterP_kernel(const int* __restrict__ src, const int* __restrict__ dst,
                                const int* __restrict__ blockcnt,
                                int* __restrict__ db, int* __restrict__ sb,
                                int* __restrict__ bucket_base) {
    __shared__ int part[256];
    __shared__ int lcur[NPART];
    int t = threadIdx.x;
    int bid = blockIdx.x;

    int v[16], s = 0;
    #pragma unroll
    for (int i = 0; i < 16; ++i) {
        int e = 16 * t + i;
        int p = e >> 9, b = e & (NB_RP - 1);
        v[i] = blockcnt[b * NPART + p];
        s += v[i];
    }
    part[t] = s;
    __syncthreads();
    for (int off = 1; off < 256; off <<= 1) {
        int u = (t >= off) ? part[t - off] : 0;
        __syncthreads();
        part[t] += u;
        __syncthreads();
    }
    int base = (t == 0) ? 0 : part[t - 1];
    #pragma unroll
    for (int i = 0; i < 16; ++i) {
        int e = 16 * t + i;
        if ((e & (NB_RP - 1)) == bid) lcur[e >> 9] = base;
        if (bid == 0 && (e & (NB_RP - 1)) == 0) bucket_base[e >> 9] = base;
        base += v[i];
    }
    if (bid == 0 && t == 0) bucket_base[NPART] = N_EDGES;
    __syncthreads();

    int e4lo = bid * CHUNK_E4;
    int e4hi = e4lo + CHUNK_E4; if (e4hi > N_EDGES / 4) e4hi = N_EDGES / 4;

    for (int e4 = e4lo + t; e4 < e4hi; e4 += 256) {
        v4i d = ((const v4i*)dst)[e4];
        v4i s4 = ((const v4i*)src)[e4];
#define PUT1(DD, SS)                                                          \
        {                                                                     \
            unsigned p = (unsigned)(DD) / NODES_PER_PART;                     \
            int pos = atomicAdd(&lcur[p], 1);                                 \
            db[pos] = (DD); sb[pos] = (SS);                                   \
        }
        PUT1(d.x, s4.x) PUT1(d.y, s4.y) PUT1(d.z, s4.z) PUT1(d.w, s4.w)
#undef PUT1
    }
}

// ---------------------------------------------------------------------------
// count_priv: block (p,sub) LDS-histograms its contiguous sub-range of
// bucket p, writes private histogram non-atomically. Zero global atomics.
// ---------------------------------------------------------------------------
__global__ void count_priv_kernel(const int* __restrict__ db,
                                  const int* __restrict__ bucket_base,
                                  int* __restrict__ privhist) {
    __shared__ int lh[NODES_PER_PART];
    int p = blockIdx.x & (NPART - 1);
    int sub = blockIdx.x >> 3;
    for (int i = threadIdx.x; i < NODES_PER_PART; i += 256) lh[i] = 0;
    __syncthreads();

    int lo = bucket_base[p], hi = bucket_base[p + 1];
    int len = hi - lo;
    int chunk = (len + SUBBLK - 1) / SUBBLK;
    int clo = lo + sub * chunk;
    int chi = clo + chunk; if (chi > hi) chi = hi;
    int nbase = p * NODES_PER_PART;

    for (int i = clo + threadIdx.x; i < chi; i += 256)
        atomicAdd(&lh[db[i] - nbase], 1);
    __syncthreads();

    int* o = privhist + (size_t)blockIdx.x * NODES_PER_PART;
    for (int i = threadIdx.x; i < NODES_PER_PART; i += 256) o[i] = lh[i];
}

// ---------------------------------------------------------------------------
// merge_hist: cnt[n] = sum of the 16 private histograms; rewrite privhist
// in place as exclusive prefixes; also emits per-block sums (bsum).
// ---------------------------------------------------------------------------
__global__ void merge_hist_kernel(int* __restrict__ privhist, int* __restrict__ cnt,
                                  int* __restrict__ bsum) {
    __shared__ int sd[256];
    int t = threadIdx.x;
    int n = blockIdx.x * 256 + t;
    int run = 0;
    if (n < N_NODES) {
        int p = n / NODES_PER_PART;
        int nl = n - p * NODES_PER_PART;
        #pragma unroll
        for (int b = 0; b < SUBBLK; ++b) {
            size_t idx = (size_t)(b * NPART + p) * NODES_PER_PART + nl;
            int v = privhist[idx];
            privhist[idx] = run;
            run += v;
        }
        cnt[n] = run;
    }
    sd[t] = (n < N_NODES) ? run : 0;
    __syncthreads();
    for (int off = 128; off > 0; off >>= 1) {
        if (t < off) sd[t] += sd[t + off];
        __syncthreads();
    }
    if (t == 0) bsum[blockIdx.x] = sd[0];
}

// ---------------------------------------------------------------------------
// scan_write: folds the 196-element bsum scan in (redundant per block),
// then per-block local exclusive scan -> row_start.
// ---------------------------------------------------------------------------
__global__ void scan_write_kernel(const int* __restrict__ cnt, const int* __restrict__ bsum,
                                  int* __restrict__ row_start) {
    __shared__ int sb_[256];
    __shared__ int sd[256];
    __shared__ int boffs;
    int t = threadIdx.x;

    int v = (t < NBLK_SCAN) ? bsum[t] : 0;
    sb_[t] = v;
    __syncthreads();
    for (int off = 1; off < 256; off <<= 1) {
        int u = (t >= off) ? sb_[t - off] : 0;
        __syncthreads();
        sb_[t] += u;
        __syncthreads();
    }
    if (t == 0) boffs = sb_[blockIdx.x] - bsum[blockIdx.x];  // exclusive offset

    int idx = blockIdx.x * 256 + t;
    int c = (idx < N_NODES) ? cnt[idx] : 0;
    sd[t] = c;
    __syncthreads();                       // also publishes boffs
    for (int off = 1; off < 256; off <<= 1) {
        int u = (t >= off) ? sd[t - off] : 0;
        __syncthreads();
        sd[t] += u;
        __syncthreads();
    }
    if (idx < N_NODES) row_start[idx] = sd[t] - c + boffs;
    if (blockIdx.x == 0 && t == 0) row_start[N_NODES] = N_EDGES;
}

// ---------------------------------------------------------------------------
// fill_det: block (p,sub) seeds LDS cursors = row_start + exclusive prefix,
// re-reads ITS db/sb sub-range, claims slots via LDS atomics, writes csr.
// ---------------------------------------------------------------------------
__global__ void fill_det_kernel(const int* __restrict__ db, const int* __restrict__ sb,
                                const int* __restrict__ bucket_base,
                                const int* __restrict__ row_start,
                                const int* __restrict__ privhist,
                                int* __restrict__ csr) {
    __shared__ int cur[NODES_PER_PART];
    int p = blockIdx.x & (NPART - 1);
    int sub = blockIdx.x >> 3;
    int nbase = p * NODES_PER_PART;
    const int* ph = privhist + (size_t)blockIdx.x * NODES_PER_PART;
    for (int i = threadIdx.x; i < NODES_PER_PART; i += 256)
        cur[i] = row_start[nbase + i] + ph[i];
    __syncthreads();

    int lo = bucket_base[p], hi = bucket_base[p + 1];
    int len = hi - lo;
    int chunk = (len + SUBBLK - 1) / SUBBLK;
    int clo = lo + sub * chunk;
    int chi = clo + chunk; if (chi > hi) chi = hi;

    for (int i = clo + threadIdx.x; i < chi; i += 256) {
        int d = db[i];
        int s = sb[i];
        int pos = atomicAdd(&cur[d - nbase], 1);
        csr[pos] = s;
    }
}

// ---------------------------------------------------------------------------
// xcvt_prep: fused x->bf16 conversion (blocks 0..3124) + weight pre-pack
// (blocks 3125..3132).
// ---------------------------------------------------------------------------
__global__ void xcvt_prep_kernel(const float* __restrict__ x, unsigned short* __restrict__ xb,
                                 const float* __restrict__ W1l, const float* __restrict__ W1r,
                                 const float* __restrict__ W2l, const float* __restrict__ W2r,
                                 unsigned short* __restrict__ Bf) {
    if (blockIdx.x < XCVT_BLOCKS) {
        int i = blockIdx.x * 256 + threadIdx.x;
        if (i >= N_NODES * DIM / 4) return;
        float4 v = ((const float4*)x)[i];
        ushort4 u;
        u.x = f2b(v.x); u.y = f2b(v.y); u.z = f2b(v.z); u.w = f2b(v.w);
        ((ushort4*)xb)[i] = u;
    } else {
        int t = (blockIdx.x - XCVT_BLOCKS) * 256 + threadIdx.x;
        if (t >= 2048) return;
        int layer = t >> 10;
        int rem = t & 1023;
        int ks = rem >> 8;
        int nt = (rem >> 6) & 3;
        int lane = rem & 63;
        int gq = lane >> 4;
        int col = nt * 16 + (lane & 15);
        const float* Wl = layer ? W2l : W1l;
        const float* Wr = layer ? W2r : W1r;
        unsigned short* o = Bf + (size_t)layer * B_STRIDE + ((ks * 4 + nt) * 64 + lane) * 8;
        #pragma unroll
        for (int i = 0; i < 8; ++i) {
            int k = ks * 32 + gq * 8 + i;
            float v = (k < DIM) ? Wl[k * DIM + col] : Wr[(k - DIM) * DIM + col];
            o[i] = f2b(v);
        }
    }
}

// ---------------------------------------------------------------------------
// Fused SAGE layer: block = 4 waves = 16 nodes (50000 = 3125 x 16 exact).
// ---------------------------------------------------------------------------
__global__ __launch_bounds__(256) void sage_fused_kernel(
        const unsigned short* __restrict__ feat,
        const int* __restrict__ row_start,
        const int* __restrict__ csr,
        const unsigned short* __restrict__ Bf,
        const float* __restrict__ bias,
        unsigned short* __restrict__ outb) {
    __shared__ unsigned short lmean[16][LMPAD];
    int n0 = blockIdx.x * 16;
    int wid = threadIdx.x >> 6;
    int lane = threadIdx.x & 63;
    int grp = lane >> 4;
    int fi = lane & 15;

    for (int rr = 0; rr < 4; ++rr) {
        int n = n0 + 4 * wid + rr;
        int rs = row_start[n], re = row_start[n + 1];

        float4 a0 = make_float4(0.f, 0.f, 0.f, 0.f);
        float4 a1 = make_float4(0.f, 0.f, 0.f, 0.f);
        int i = rs;
        for (; i + 8 <= re; i += 8) {
            int s0 = csr[i + grp];
            int s1 = csr[i + 4 + grp];
            ushort4 u0 = ((const ushort4*)(feat + (size_t)s0 * DIM))[fi];
            ushort4 u1 = ((const ushort4*)(feat + (size_t)s1 * DIM))[fi];
            a0.x += b2f(u0.x); a0.y += b2f(u0.y); a0.z += b2f(u0.z); a0.w += b2f(u0.w);
            a1.x += b2f(u1.x); a1.y += b2f(u1.y); a1.z += b2f(u1.z); a1.w += b2f(u1.w);
        }
        if (i + 4 <= re) {
            int s = csr[i + grp];
            ushort4 u = ((const ushort4*)(feat + (size_t)s * DIM))[fi];
            a0.x += b2f(u.x); a0.y += b2f(u.y); a0.z += b2f(u.z); a0.w += b2f(u.w);
            i += 4;
        }
        if (i + grp < re) {
            int s = csr[i + grp];
            ushort4 u = ((const ushort4*)(feat + (size_t)s * DIM))[fi];
            a1.x += b2f(u.x); a1.y += b2f(u.y); a1.z += b2f(u.z); a1.w += b2f(u.w);
        }
        float4 acc = make_float4(a0.x + a1.x, a0.y + a1.y, a0.z + a1.z, a0.w + a1.w);

        acc.x += __shfl_xor(acc.x, 16); acc.y += __shfl_xor(acc.y, 16);
        acc.z += __shfl_xor(acc.z, 16); acc.w += __shfl_xor(acc.w, 16);
        acc.x += __shfl_xor(acc.x, 32); acc.y += __shfl_xor(acc.y, 32);
        acc.z += __shfl_xor(acc.z, 32); acc.w += __shfl_xor(acc.w, 32);

        if (grp == 0) {
            float inv = 1.0f / fmaxf((float)(re - rs), 1.0f);
            ushort4 m;
            m.x = f2b(acc.x * inv); m.y = f2b(acc.y * inv);
            m.z = f2b(acc.z * inv); m.w = f2b(acc.w * inv);
            ((ushort4*)&lmean[4 * wid + rr][0])[fi] = m;
        }
    }
    __syncthreads();

    const short8* Bv = (const short8*)Bf;
    short8 bk0 = Bv[(0 * 4 + wid) * 64 + lane];
    short8 bk1 = Bv[(1 * 4 + wid) * 64 + lane];
    short8 bk2 = Bv[(2 * 4 + wid) * 64 + lane];
    short8 bk3 = Bv[(3 * 4 + wid) * 64 + lane];

    int g = lane >> 4;
    int r = lane & 15;
    f32x4 acc = {0.f, 0.f, 0.f, 0.f};

    short8 a;
    a = *(const short8*)&lmean[r][g * 8];
    acc = __builtin_amdgcn_mfma_f32_16x16x32_bf16(a, bk0, acc, 0, 0, 0);
    a = *(const short8*)&lmean[r][32 + g * 8];
    acc = __builtin_amdgcn_mfma_f32_16x16x32_bf16(a, bk1, acc, 0, 0, 0);
    const unsigned short* axp = feat + (size_t)(n0 + r) * DIM + g * 8;
    a = *(const short8*)(axp);
    acc = __builtin_amdgcn_mfma_f32_16x16x32_bf16(a, bk2, acc, 0, 0, 0);
    a = *(const short8*)(axp + 32);
    acc = __builtin_amdgcn_mfma_f32_16x16x32_bf16(a, bk3, acc, 0, 0, 0);

    float bc = bias[wid * 16 + r];
    #pragma unroll
    for (int i = 0; i < 4; ++i) {
        float v = fmaxf(acc[i] + bc, 0.0f);
        outb[(size_t)(n0 + 4 * g + i) * DIM + wid * 16 + r] = f2b(v);
    }
}

// ---------------------------------------------------------------------------
// pool_fc: one block per graph. Binary-search the sorted batch array for the
// graph's node range, 4-wave column-sum (fp32) over its rows, LDS reduce,
// then the 64x8 FC in-block. Replaces pool_b + fc + psum atomics/zeroing.
// ---------------------------------------------------------------------------
__global__ void pool_fc_kernel(const unsigned short* __restrict__ h,
                               const int* __restrict__ batch,
                               const float* __restrict__ Wfc,
                               const float* __restrict__ bfc,
                               float* __restrict__ out) {
    __shared__ float cs[4][DIM];
    __shared__ float colsum[DIM];
    int g = blockIdx.x;
    int tid = threadIdx.x;
    int wid = tid >> 6, j = tid & 63;

    // lower_bound(batch, g) and lower_bound(batch, g+1) — uniform per block
    int lo = 0, hi = N_NODES;
    while (lo < hi) { int m = (lo + hi) >> 1; if (batch[m] < g) lo = m + 1; else hi = m; }
    int glo = lo;
    lo = 0; hi = N_NODES;
    while (lo < hi) { int m = (lo + hi) >> 1; if (batch[m] < g + 1) lo = m + 1; else hi = m; }
    int ghi = lo;

    float acc = 0.0f;
    for (int n = glo + wid; n < ghi; n += 4)
        acc += b2f(h[(size_t)n * DIM + j]);
    cs[wid][j] = acc;
    __syncthreads();
    if (wid == 0) colsum[j] = cs[0][j] + cs[1][j] + cs[2][j] + cs[3][j];
    __syncthreads();

    if (tid < OUT_DIM) {
        float inv = 1.0f / fmaxf((float)(ghi - glo), 1.0f);
        float s = bfc[tid];
        #pragma unroll
        for (int k = 0; k < DIM; ++k)
            s += colsum[k] * inv * Wfc[k * OUT_DIM + tid];
        out[g * OUT_DIM + tid] = s;
    }
}

extern "C" void kernel_launch(void* const* d_in, const int* in_sizes, int n_in,
                              void* d_out, int out_size, void* d_ws, size_t ws_size,
                              hipStream_t stream) {
    const float* x   = (const float*)d_in[0];
    const int* ei    = (const int*)d_in[1];
    const int* batch = (const int*)d_in[2];
    const float* W1l = (const float*)d_in[3];
    const float* b1  = (const float*)d_in[4];
    const float* W1r = (const float*)d_in[5];
    const float* W2l = (const float*)d_in[6];
    const float* b2  = (const float*)d_in[7];
    const float* W2r = (const float*)d_in[8];
    const float* Wfc = (const float*)d_in[9];
    const float* bfc = (const float*)d_in[10];
    float* out = (float*)d_out;

    const int* src = ei;
    const int* dst = ei + N_EDGES;

    // ---- workspace layout (~30 MB). Region A time-shared: build-phase
    // db/sb/privhist, then bf16 feature buffers (stream-ordered). ----
    const size_t SZ_BF   = (size_t)N_NODES * DIM * 2;              // 6.4 MB
    const size_t SZ_CSR  = (size_t)N_EDGES * sizeof(int);          // 4 MB
    const size_t SZ_CNT  = ((size_t)(N_NODES + 1) * sizeof(int) + 255) & ~(size_t)255;
    char* ws = (char*)d_ws;
    int*   csr       = (int*)(ws);
    int*   cnt       = (int*)(ws + SZ_CSR);
    int*   row_start = (int*)(ws + SZ_CSR + SZ_CNT);
    char*  tail      = ws + SZ_CSR + 2 * SZ_CNT;
    int*   bsum      = (int*)(tail);
    int*   boff      = bsum + 256;                   // unused slot, layout stability
    int*   blockcnt  = boff + 256;
    int*   abs_off   = blockcnt + NB_RP * NPART;     // unused slot, layout stability
    int*   bucket_base = abs_off + NB_RP * NPART;
    unsigned short* Bf = (unsigned short*)(bucket_base + 16);
    float* psum      = (float*)((char*)Bf + 2 * B_STRIDE * 2);     // unused
    float* pcnt      = psum + N_GRAPHS * DIM;                      // unused
    char*  regionA   = (char*)(pcnt + N_GRAPHS) + 4096;
    regionA = (char*)(((size_t)regionA + 255) & ~(size_t)255);
    // build-phase aliases
    int*   db        = (int*)(regionA);
    int*   sb        = (int*)(regionA + SZ_CSR);
    int*   privhist  = (int*)(regionA + 2 * SZ_CSR);
    // compute-phase aliases
    unsigned short* xb    = (unsigned short*)(regionA);
    unsigned short* h1b   = (unsigned short*)(regionA + SZ_BF);
    unsigned short* h2b   = (unsigned short*)(regionA + 2 * SZ_BF);

    const int fusedBlocks = N_NODES / 16;                          // 3125 exact

    // ---- CSR build: deterministic two-pass counting sort, no global atomics
    histB_kernel<<<NB_RP, 256, 0, stream>>>(dst, blockcnt);
    scatterP_kernel<<<NB_RP, 256, 0, stream>>>(src, dst, blockcnt, db, sb, bucket_base);
    count_priv_kernel<<<NPART * SUBBLK, 256, 0, stream>>>(db, bucket_base, privhist);
    merge_hist_kernel<<<NBLK_SCAN, 256, 0, stream>>>(privhist, cnt, bsum);
    scan_write_kernel<<<NBLK_SCAN, 256, 0, stream>>>(cnt, bsum, row_start);
    fill_det_kernel<<<NPART * SUBBLK, 256, 0, stream>>>(db, sb, bucket_base, row_start,
                                                        privhist, csr);

    // ---- bf16 conversion + weight pre-pack (one dispatch) ----
    xcvt_prep_kernel<<<XCVT_BLOCKS + 8, 256, 0, stream>>>(x, xb, W1l, W1r, W2l, W2r, Bf);

    // ---- Layer 1 + Layer 2 (fused gather+GEMM) ----
    sage_fused_kernel<<<fusedBlocks, 256, 0, stream>>>(xb, row_start, csr, Bf, b1, h1b);
    sage_fused_kernel<<<fusedBlocks, 256, 0, stream>>>(h1b, row_start, csr,
                                                       Bf + B_STRIDE, b2, h2b);
    // ---- Pool + FC (one kernel, block per graph) ----
    pool_fc_kernel<<<N_GRAPHS, 256, 0, stream>>>(h2b, batch, Wfc, bfc, out);
}

// Round 20
// 151.554 us; speedup vs baseline: 1.1776x; 1.1776x over previous
//
#include <hip/hip_runtime.h>
#include <hip/hip_bf16.h>

#define N_NODES 50000
#define N_EDGES 1000000
#define DIM 64
#define N_GRAPHS 64
#define OUT_DIM 8
#define NBLK_SCAN 196         // ceil(50000/256)
#define NPART 8               // one dst-range partition per XCD
#define SUBBLK 16             // blocks per partition (count_priv / fill_det)
#define NODES_PER_PART (N_NODES / NPART)   // 6250
#define NB_RP 512             // chunked radix-partition blocks
#define CHUNK_E4 489          // ceil(250000/512)
#define B_STRIDE 8192         // bf16 elements per packed weight layer (128x64)
#define POOL_NPW 64           // pool: nodes per wave
#define LMPAD 80              // LDS mean-row stride (shorts): 160B, 16B-aligned
#define XCVT_BLOCKS 3125      // N_NODES*DIM/4/256

typedef __attribute__((ext_vector_type(8))) short short8;   // 8 bf16 = 4 VGPR
typedef __attribute__((ext_vector_type(4))) float f32x4;    // MFMA C/D
typedef __attribute__((ext_vector_type(4))) int v4i;

__device__ __forceinline__ unsigned short f2b(float f) {
    __hip_bfloat16 h = __float2bfloat16(f);
    return *reinterpret_cast<unsigned short*>(&h);
}
__device__ __forceinline__ float b2f(unsigned short u) {
    __hip_bfloat16 h = *reinterpret_cast<__hip_bfloat16*>(&u);
    return __bfloat162float(h);
}

// ---------------------------------------------------------------------------
// histB: per-chunk 8-bucket counts (VGPR if-chain + shfl reduce).
// Block 0 also zeroes psum/pcnt (pool_b needs them zeroed).
// ---------------------------------------------------------------------------
__global__ void histB_kernel(const int* __restrict__ dst, int* __restrict__ blockcnt,
                             float* __restrict__ psum) {
    if (blockIdx.x == 0) {
        for (int i = threadIdx.x; i < N_GRAPHS * DIM + N_GRAPHS; i += 256)
            psum[i] = 0.0f;
    }
    __shared__ int sc[NPART];
    if (threadIdx.x < NPART) sc[threadIdx.x] = 0;
    __syncthreads();

    int e4lo = blockIdx.x * CHUNK_E4;
    int e4hi = e4lo + CHUNK_E4; if (e4hi > N_EDGES / 4) e4hi = N_EDGES / 4;

    int c0 = 0, c1 = 0, c2 = 0, c3 = 0, c4 = 0, c5 = 0, c6 = 0, c7 = 0;
    for (int e4 = e4lo + threadIdx.x; e4 < e4hi; e4 += 256) {
        v4i d = ((const v4i*)dst)[e4];
#define CNT1(DD)                                                              \
        {                                                                     \
            unsigned p = (unsigned)(DD) / NODES_PER_PART;                     \
            c0 += (p == 0); c1 += (p == 1); c2 += (p == 2); c3 += (p == 3);   \
            c4 += (p == 4); c5 += (p == 5); c6 += (p == 6); c7 += (p == 7);   \
        }
        CNT1(d.x) CNT1(d.y) CNT1(d.z) CNT1(d.w)
#undef CNT1
    }
    #pragma unroll
    for (int off = 32; off > 0; off >>= 1) {
        c0 += __shfl_xor(c0, off); c1 += __shfl_xor(c1, off);
        c2 += __shfl_xor(c2, off); c3 += __shfl_xor(c3, off);
        c4 += __shfl_xor(c4, off); c5 += __shfl_xor(c5, off);
        c6 += __shfl_xor(c6, off); c7 += __shfl_xor(c7, off);
    }
    if ((threadIdx.x & 63) == 0) {
        atomicAdd(&sc[0], c0); atomicAdd(&sc[1], c1);
        atomicAdd(&sc[2], c2); atomicAdd(&sc[3], c3);
        atomicAdd(&sc[4], c4); atomicAdd(&sc[5], c5);
        atomicAdd(&sc[6], c6); atomicAdd(&sc[7], c7);
    }
    __syncthreads();
    if (threadIdx.x < NPART) blockcnt[blockIdx.x * NPART + threadIdx.x] = sc[threadIdx.x];
}

// ---------------------------------------------------------------------------
// scatterP (scan8 inlined): each block redundantly scans the 4096
// bucket-major blockcnt entries in LDS, extracts its own 8 cursors,
// block 0 writes bucket_base. Then the bucketed scatter.
// ---------------------------------------------------------------------------
__global__ void scatterP_kernel(const int* __restrict__ src, const int* __restrict__ dst,
                                const int* __restrict__ blockcnt,
                                int* __restrict__ db, int* __restrict__ sb,
                                int* __restrict__ bucket_base) {
    __shared__ int part[256];
    __shared__ int lcur[NPART];
    int t = threadIdx.x;
    int bid = blockIdx.x;

    int v[16], s = 0;
    #pragma unroll
    for (int i = 0; i < 16; ++i) {
        int e = 16 * t + i;
        int p = e >> 9, b = e & (NB_RP - 1);
        v[i] = blockcnt[b * NPART + p];
        s += v[i];
    }
    part[t] = s;
    __syncthreads();
    for (int off = 1; off < 256; off <<= 1) {
        int u = (t >= off) ? part[t - off] : 0;
        __syncthreads();
        part[t] += u;
        __syncthreads();
    }
    int base = (t == 0) ? 0 : part[t - 1];
    #pragma unroll
    for (int i = 0; i < 16; ++i) {
        int e = 16 * t + i;
        if ((e & (NB_RP - 1)) == bid) lcur[e >> 9] = base;
        if (bid == 0 && (e & (NB_RP - 1)) == 0) bucket_base[e >> 9] = base;
        base += v[i];
    }
    if (bid == 0 && t == 0) bucket_base[NPART] = N_EDGES;
    __syncthreads();

    int e4lo = bid * CHUNK_E4;
    int e4hi = e4lo + CHUNK_E4; if (e4hi > N_EDGES / 4) e4hi = N_EDGES / 4;

    for (int e4 = e4lo + t; e4 < e4hi; e4 += 256) {
        v4i d = ((const v4i*)dst)[e4];
        v4i s4 = ((const v4i*)src)[e4];
#define PUT1(DD, SS)                                                          \
        {                                                                     \
            unsigned p = (unsigned)(DD) / NODES_PER_PART;                     \
            int pos = atomicAdd(&lcur[p], 1);                                 \
            db[pos] = (DD); sb[pos] = (SS);                                   \
        }
        PUT1(d.x, s4.x) PUT1(d.y, s4.y) PUT1(d.z, s4.z) PUT1(d.w, s4.w)
#undef PUT1
    }
}

// ---------------------------------------------------------------------------
// count_priv: block (p,sub) LDS-histograms its contiguous sub-range of
// bucket p, writes private histogram non-atomically. Zero global atomics.
// ---------------------------------------------------------------------------
__global__ void count_priv_kernel(const int* __restrict__ db,
                                  const int* __restrict__ bucket_base,
                                  int* __restrict__ privhist) {
    __shared__ int lh[NODES_PER_PART];
    int p = blockIdx.x & (NPART - 1);
    int sub = blockIdx.x >> 3;
    for (int i = threadIdx.x; i < NODES_PER_PART; i += 256) lh[i] = 0;
    __syncthreads();

    int lo = bucket_base[p], hi = bucket_base[p + 1];
    int len = hi - lo;
    int chunk = (len + SUBBLK - 1) / SUBBLK;
    int clo = lo + sub * chunk;
    int chi = clo + chunk; if (chi > hi) chi = hi;
    int nbase = p * NODES_PER_PART;

    for (int i = clo + threadIdx.x; i < chi; i += 256)
        atomicAdd(&lh[db[i] - nbase], 1);
    __syncthreads();

    int* o = privhist + (size_t)blockIdx.x * NODES_PER_PART;
    for (int i = threadIdx.x; i < NODES_PER_PART; i += 256) o[i] = lh[i];
}

// ---------------------------------------------------------------------------
// merge_hist: cnt[n] = sum of the 16 private histograms; rewrite privhist
// in place as exclusive prefixes; also emits per-block sums (bsum).
// ---------------------------------------------------------------------------
__global__ void merge_hist_kernel(int* __restrict__ privhist, int* __restrict__ cnt,
                                  int* __restrict__ bsum) {
    __shared__ int sd[256];
    int t = threadIdx.x;
    int n = blockIdx.x * 256 + t;
    int run = 0;
    if (n < N_NODES) {
        int p = n / NODES_PER_PART;
        int nl = n - p * NODES_PER_PART;
        #pragma unroll
        for (int b = 0; b < SUBBLK; ++b) {
            size_t idx = (size_t)(b * NPART + p) * NODES_PER_PART + nl;
            int v = privhist[idx];
            privhist[idx] = run;
            run += v;
        }
        cnt[n] = run;
    }
    sd[t] = (n < N_NODES) ? run : 0;
    __syncthreads();
    for (int off = 128; off > 0; off >>= 1) {
        if (t < off) sd[t] += sd[t + off];
        __syncthreads();
    }
    if (t == 0) bsum[blockIdx.x] = sd[0];
}

// ---------------------------------------------------------------------------
// scan_write: folds the 196-element bsum scan in (redundant per block),
// then per-block local exclusive scan -> row_start.
// ---------------------------------------------------------------------------
__global__ void scan_write_kernel(const int* __restrict__ cnt, const int* __restrict__ bsum,
                                  int* __restrict__ row_start) {
    __shared__ int sb_[256];
    __shared__ int sd[256];
    __shared__ int boffs;
    int t = threadIdx.x;

    int v = (t < NBLK_SCAN) ? bsum[t] : 0;
    sb_[t] = v;
    __syncthreads();
    for (int off = 1; off < 256; off <<= 1) {
        int u = (t >= off) ? sb_[t - off] : 0;
        __syncthreads();
        sb_[t] += u;
        __syncthreads();
    }
    if (t == 0) boffs = sb_[blockIdx.x] - bsum[blockIdx.x];  // exclusive offset

    int idx = blockIdx.x * 256 + t;
    int c = (idx < N_NODES) ? cnt[idx] : 0;
    sd[t] = c;
    __syncthreads();                       // also publishes boffs
    for (int off = 1; off < 256; off <<= 1) {
        int u = (t >= off) ? sd[t - off] : 0;
        __syncthreads();
        sd[t] += u;
        __syncthreads();
    }
    if (idx < N_NODES) row_start[idx] = sd[t] - c + boffs;
    if (blockIdx.x == 0 && t == 0) row_start[N_NODES] = N_EDGES;
}

// ---------------------------------------------------------------------------
// fill_det: block (p,sub) seeds LDS cursors = row_start + exclusive prefix,
// re-reads ITS db/sb sub-range, claims slots via LDS atomics, writes csr.
// ---------------------------------------------------------------------------
__global__ void fill_det_kernel(const int* __restrict__ db, const int* __restrict__ sb,
                                const int* __restrict__ bucket_base,
                                const int* __restrict__ row_start,
                                const int* __restrict__ privhist,
                                int* __restrict__ csr) {
    __shared__ int cur[NODES_PER_PART];
    int p = blockIdx.x & (NPART - 1);
    int sub = blockIdx.x >> 3;
    int nbase = p * NODES_PER_PART;
    const int* ph = privhist + (size_t)blockIdx.x * NODES_PER_PART;
    for (int i = threadIdx.x; i < NODES_PER_PART; i += 256)
        cur[i] = row_start[nbase + i] + ph[i];
    __syncthreads();

    int lo = bucket_base[p], hi = bucket_base[p + 1];
    int len = hi - lo;
    int chunk = (len + SUBBLK - 1) / SUBBLK;
    int clo = lo + sub * chunk;
    int chi = clo + chunk; if (chi > hi) chi = hi;

    for (int i = clo + threadIdx.x; i < chi; i += 256) {
        int d = db[i];
        int s = sb[i];
        int pos = atomicAdd(&cur[d - nbase], 1);
        csr[pos] = s;
    }
}

// ---------------------------------------------------------------------------
// xcvt_prep: fused x->bf16 conversion (blocks 0..3124) + weight pre-pack
// (blocks 3125..3132).
// ---------------------------------------------------------------------------
__global__ void xcvt_prep_kernel(const float* __restrict__ x, unsigned short* __restrict__ xb,
                                 const float* __restrict__ W1l, const float* __restrict__ W1r,
                                 const float* __restrict__ W2l, const float* __restrict__ W2r,
                                 unsigned short* __restrict__ Bf) {
    if (blockIdx.x < XCVT_BLOCKS) {
        int i = blockIdx.x * 256 + threadIdx.x;
        if (i >= N_NODES * DIM / 4) return;
        float4 v = ((const float4*)x)[i];
        ushort4 u;
        u.x = f2b(v.x); u.y = f2b(v.y); u.z = f2b(v.z); u.w = f2b(v.w);
        ((ushort4*)xb)[i] = u;
    } else {
        int t = (blockIdx.x - XCVT_BLOCKS) * 256 + threadIdx.x;
        if (t >= 2048) return;
        int layer = t >> 10;
        int rem = t & 1023;
        int ks = rem >> 8;
        int nt = (rem >> 6) & 3;
        int lane = rem & 63;
        int gq = lane >> 4;
        int col = nt * 16 + (lane & 15);
        const float* Wl = layer ? W2l : W1l;
        const float* Wr = layer ? W2r : W1r;
        unsigned short* o = Bf + (size_t)layer * B_STRIDE + ((ks * 4 + nt) * 64 + lane) * 8;
        #pragma unroll
        for (int i = 0; i < 8; ++i) {
            int k = ks * 32 + gq * 8 + i;
            float v = (k < DIM) ? Wl[k * DIM + col] : Wr[(k - DIM) * DIM + col];
            o[i] = f2b(v);
        }
    }
}

// ---------------------------------------------------------------------------
// Fused SAGE layer: block = 4 waves = 16 nodes (50000 = 3125 x 16 exact).
// ---------------------------------------------------------------------------
__global__ __launch_bounds__(256) void sage_fused_kernel(
        const unsigned short* __restrict__ feat,
        const int* __restrict__ row_start,
        const int* __restrict__ csr,
        const unsigned short* __restrict__ Bf,
        const float* __restrict__ bias,
        unsigned short* __restrict__ outb) {
    __shared__ unsigned short lmean[16][LMPAD];
    int n0 = blockIdx.x * 16;
    int wid = threadIdx.x >> 6;
    int lane = threadIdx.x & 63;
    int grp = lane >> 4;
    int fi = lane & 15;

    for (int rr = 0; rr < 4; ++rr) {
        int n = n0 + 4 * wid + rr;
        int rs = row_start[n], re = row_start[n + 1];

        float4 a0 = make_float4(0.f, 0.f, 0.f, 0.f);
        float4 a1 = make_float4(0.f, 0.f, 0.f, 0.f);
        int i = rs;
        for (; i + 8 <= re; i += 8) {
            int s0 = csr[i + grp];
            int s1 = csr[i + 4 + grp];
            ushort4 u0 = ((const ushort4*)(feat + (size_t)s0 * DIM))[fi];
            ushort4 u1 = ((const ushort4*)(feat + (size_t)s1 * DIM))[fi];
            a0.x += b2f(u0.x); a0.y += b2f(u0.y); a0.z += b2f(u0.z); a0.w += b2f(u0.w);
            a1.x += b2f(u1.x); a1.y += b2f(u1.y); a1.z += b2f(u1.z); a1.w += b2f(u1.w);
        }
        if (i + 4 <= re) {
            int s = csr[i + grp];
            ushort4 u = ((const ushort4*)(feat + (size_t)s * DIM))[fi];
            a0.x += b2f(u.x); a0.y += b2f(u.y); a0.z += b2f(u.z); a0.w += b2f(u.w);
            i += 4;
        }
        if (i + grp < re) {
            int s = csr[i + grp];
            ushort4 u = ((const ushort4*)(feat + (size_t)s * DIM))[fi];
            a1.x += b2f(u.x); a1.y += b2f(u.y); a1.z += b2f(u.z); a1.w += b2f(u.w);
        }
        float4 acc = make_float4(a0.x + a1.x, a0.y + a1.y, a0.z + a1.z, a0.w + a1.w);

        acc.x += __shfl_xor(acc.x, 16); acc.y += __shfl_xor(acc.y, 16);
        acc.z += __shfl_xor(acc.z, 16); acc.w += __shfl_xor(acc.w, 16);
        acc.x += __shfl_xor(acc.x, 32); acc.y += __shfl_xor(acc.y, 32);
        acc.z += __shfl_xor(acc.z, 32); acc.w += __shfl_xor(acc.w, 32);

        if (grp == 0) {
            float inv = 1.0f / fmaxf((float)(re - rs), 1.0f);
            ushort4 m;
            m.x = f2b(acc.x * inv); m.y = f2b(acc.y * inv);
            m.z = f2b(acc.z * inv); m.w = f2b(acc.w * inv);
            ((ushort4*)&lmean[4 * wid + rr][0])[fi] = m;
        }
    }
    __syncthreads();

    const short8* Bv = (const short8*)Bf;
    short8 bk0 = Bv[(0 * 4 + wid) * 64 + lane];
    short8 bk1 = Bv[(1 * 4 + wid) * 64 + lane];
    short8 bk2 = Bv[(2 * 4 + wid) * 64 + lane];
    short8 bk3 = Bv[(3 * 4 + wid) * 64 + lane];

    int g = lane >> 4;
    int r = lane & 15;
    f32x4 acc = {0.f, 0.f, 0.f, 0.f};

    short8 a;
    a = *(const short8*)&lmean[r][g * 8];
    acc = __builtin_amdgcn_mfma_f32_16x16x32_bf16(a, bk0, acc, 0, 0, 0);
    a = *(const short8*)&lmean[r][32 + g * 8];
    acc = __builtin_amdgcn_mfma_f32_16x16x32_bf16(a, bk1, acc, 0, 0, 0);
    const unsigned short* axp = feat + (size_t)(n0 + r) * DIM + g * 8;
    a = *(const short8*)(axp);
    acc = __builtin_amdgcn_mfma_f32_16x16x32_bf16(a, bk2, acc, 0, 0, 0);
    a = *(const short8*)(axp + 32);
    acc = __builtin_amdgcn_mfma_f32_16x16x32_bf16(a, bk3, acc, 0, 0, 0);

    float bc = bias[wid * 16 + r];
    #pragma unroll
    for (int i = 0; i < 4; ++i) {
        float v = fmaxf(acc[i] + bc, 0.0f);
        outb[(size_t)(n0 + 4 * g + i) * DIM + wid * 16 + r] = f2b(v);
    }
}

// ---------------------------------------------------------------------------
// Global mean pool — 64 nodes/wave segmented reduction (batch sorted).
// ---------------------------------------------------------------------------
__global__ void pool_b_kernel(const unsigned short* __restrict__ h,
                              const int* __restrict__ batch,
                              float* __restrict__ psum, float* __restrict__ pcnt) {
    int wv = (blockIdx.x * blockDim.x + threadIdx.x) >> 6;
    int start = wv * POOL_NPW;
    if (start >= N_NODES) return;
    int j = threadIdx.x & 63;
    int end = start + POOL_NPW;
    if (end > N_NODES) end = N_NODES;

    int g = batch[start];
    float acc = 0.0f, cnt = 0.0f;
    for (int n = start; n < end; ++n) {
        int gn = batch[n];
        if (gn != g) {
            atomicAdd(&psum[g * DIM + j], acc);
            if (j == 0) atomicAdd(&pcnt[g], cnt);
            g = gn; acc = 0.0f; cnt = 0.0f;
        }
        acc += b2f(h[(size_t)n * DIM + j]);
        cnt += 1.0f;
    }
    atomicAdd(&psum[g * DIM + j], acc);
    if (j == 0) atomicAdd(&pcnt[g], cnt);
}

// ---------------------------------------------------------------------------
// Final FC: out[g][o] = (psum[g]/max(cnt,1)) @ Wfc + bfc   (64 x 8, fp32)
// ---------------------------------------------------------------------------
__global__ void fc_kernel(const float* __restrict__ psum,
                          const float* __restrict__ pcnt,
                          const float* __restrict__ Wfc,
                          const float* __restrict__ bfc,
                          float* __restrict__ out) {
    int tid = threadIdx.x;
    if (tid >= N_GRAPHS * OUT_DIM) return;
    int g = tid >> 3;
    int o = tid & 7;
    float inv = 1.0f / fmaxf(pcnt[g], 1.0f);
    float s = bfc[o];
    #pragma unroll
    for (int k = 0; k < DIM; ++k) {
        s += psum[g * DIM + k] * inv * Wfc[k * OUT_DIM + o];
    }
    out[g * OUT_DIM + o] = s;
}

extern "C" void kernel_launch(void* const* d_in, const int* in_sizes, int n_in,
                              void* d_out, int out_size, void* d_ws, size_t ws_size,
                              hipStream_t stream) {
    const float* x   = (const float*)d_in[0];
    const int* ei    = (const int*)d_in[1];
    const int* batch = (const int*)d_in[2];
    const float* W1l = (const float*)d_in[3];
    const float* b1  = (const float*)d_in[4];
    const float* W1r = (const float*)d_in[5];
    const float* W2l = (const float*)d_in[6];
    const float* b2  = (const float*)d_in[7];
    const float* W2r = (const float*)d_in[8];
    const float* Wfc = (const float*)d_in[9];
    const float* bfc = (const float*)d_in[10];
    float* out = (float*)d_out;

    const int* src = ei;
    const int* dst = ei + N_EDGES;

    // ---- workspace layout (~30 MB). Region A time-shared: build-phase
    // db/sb/privhist, then bf16 feature buffers (stream-ordered). ----
    const size_t SZ_BF   = (size_t)N_NODES * DIM * 2;              // 6.4 MB
    const size_t SZ_CSR  = (size_t)N_EDGES * sizeof(int);          // 4 MB
    const size_t SZ_CNT  = ((size_t)(N_NODES + 1) * sizeof(int) + 255) & ~(size_t)255;
    char* ws = (char*)d_ws;
    int*   csr       = (int*)(ws);
    int*   cnt       = (int*)(ws + SZ_CSR);
    int*   row_start = (int*)(ws + SZ_CSR + SZ_CNT);
    char*  tail      = ws + SZ_CSR + 2 * SZ_CNT;
    int*   bsum      = (int*)(tail);
    int*   boff      = bsum + 256;                   // unused slot, layout stability
    int*   blockcnt  = boff + 256;
    int*   abs_off   = blockcnt + NB_RP * NPART;     // unused slot, layout stability
    int*   bucket_base = abs_off + NB_RP * NPART;
    unsigned short* Bf = (unsigned short*)(bucket_base + 16);
    float* psum      = (float*)((char*)Bf + 2 * B_STRIDE * 2);
    float* pcnt      = psum + N_GRAPHS * DIM;
    char*  regionA   = (char*)(pcnt + N_GRAPHS) + 4096;
    regionA = (char*)(((size_t)regionA + 255) & ~(size_t)255);
    // build-phase aliases
    int*   db        = (int*)(regionA);
    int*   sb        = (int*)(regionA + SZ_CSR);
    int*   privhist  = (int*)(regionA + 2 * SZ_CSR);
    // compute-phase aliases
    unsigned short* xb    = (unsigned short*)(regionA);
    unsigned short* h1b   = (unsigned short*)(regionA + SZ_BF);
    unsigned short* h2b   = (unsigned short*)(regionA + 2 * SZ_BF);

    const int fusedBlocks = N_NODES / 16;                          // 3125 exact
    const int poolWaves   = (N_NODES + POOL_NPW - 1) / POOL_NPW;   // 782
    const int poolBlocks  = (poolWaves + 3) / 4;                   // 196

    // ---- CSR build: deterministic two-pass counting sort, no global atomics
    histB_kernel<<<NB_RP, 256, 0, stream>>>(dst, blockcnt, psum);
    scatterP_kernel<<<NB_RP, 256, 0, stream>>>(src, dst, blockcnt, db, sb, bucket_base);
    count_priv_kernel<<<NPART * SUBBLK, 256, 0, stream>>>(db, bucket_base, privhist);
    merge_hist_kernel<<<NBLK_SCAN, 256, 0, stream>>>(privhist, cnt, bsum);
    scan_write_kernel<<<NBLK_SCAN, 256, 0, stream>>>(cnt, bsum, row_start);
    fill_det_kernel<<<NPART * SUBBLK, 256, 0, stream>>>(db, sb, bucket_base, row_start,
                                                        privhist, csr);

    // ---- bf16 conversion + weight pre-pack (one dispatch) ----
    xcvt_prep_kernel<<<XCVT_BLOCKS + 8, 256, 0, stream>>>(x, xb, W1l, W1r, W2l, W2r, Bf);

    // ---- Layer 1 + Layer 2 (fused gather+GEMM) ----
    sage_fused_kernel<<<fusedBlocks, 256, 0, stream>>>(xb, row_start, csr, Bf, b1, h1b);
    sage_fused_kernel<<<fusedBlocks, 256, 0, stream>>>(h1b, row_start, csr,
                                                       Bf + B_STRIDE, b2, h2b);
    // ---- Pool + FC ----
    pool_b_kernel<<<poolBlocks, 256, 0, stream>>>(h2b, batch, psum, pcnt);
    fc_kernel<<<1, 512, 0, stream>>>(psum, pcnt, Wfc, bfc, out);
}